// Round 1
// baseline (556.018 us; speedup 1.0000x reference)
//
#include <hip/hip_runtime.h>

#define NJ   16
#define DM   128
#define NH   8
#define HDIM 16

// Kinematic adjacency (compile-time constant of the reference):
// skeleton edges = 1.0 (sym), symmetry pairs += 0.8 (sym), + identity.
__constant__ float c_adj[NJ * NJ] = {
    // row 0
    1,1,0,0, 1,0,0,1, 0,0,1,0, 0,1,0,0,
    // row 1
    1,1,1,0, 0,0,0,0, 0,0,0,0, 0,0,0,0,
    // row 2
    0,1,1,1, 0,0,0,0, 0,0,0,0, 0,0,0,0,
    // row 3
    0,0,1,1, 0,0,0,0, 0,0,0,0, 0,0,0,0,
    // row 4
    1,0,0,0, 1,1,0,0.8f, 0,0,0,0, 0,0,0,0,
    // row 5
    0,0,0,0, 1,1,1,0, 0.8f,0,0,0, 0,0,0,0,
    // row 6
    0,0,0,0, 0,1,1,0, 0,0.8f,0,0, 0,0,0,0,
    // row 7
    1,0,0,0, 0.8f,0,0,1, 1,0,0,0, 0,0,0,0,
    // row 8
    0,0,0,0, 0,0.8f,0,1, 1,1,0,0, 0,0,0,0,
    // row 9
    0,0,0,0, 0,0,0.8f,0, 1,1,0,0, 0,0,0,0,
    // row 10
    1,0,0,0, 0,0,0,0, 0,0,1,1, 0,0.8f,0,0,
    // row 11
    0,0,0,0, 0,0,0,0, 0,0,1,1, 1,0,0.8f,0,
    // row 12
    0,0,0,0, 0,0,0,0, 0,0,0,1, 1,0,0,0.8f,
    // row 13
    1,0,0,0, 0,0,0,0, 0,0,0.8f,0, 0,1,1,0,
    // row 14
    0,0,0,0, 0,0,0,0, 0,0,0,0.8f, 0,1,1,1,
    // row 15
    0,0,0,0, 0,0,0,0, 0,0,0,0, 0.8f,0,1,1
};

__device__ __forceinline__ float dot4(float4 a, float4 b) {
    return a.x * b.x + a.y * b.y + a.z * b.z + a.w * b.w;
}

__global__ __launch_bounds__(128) void skel_attn_kernel(
    const float* __restrict__ x,
    const float* __restrict__ Wq, const float* __restrict__ bq,
    const float* __restrict__ Wk, const float* __restrict__ bk,
    const float* __restrict__ Wv, const float* __restrict__ bv,
    const float* __restrict__ Wo, const float* __restrict__ bo,
    float* __restrict__ out)
{
    const int pos = blockIdx.x;          // b*S + s
    const int t   = threadIdx.x;         // 0..127

    __shared__ float sx[NJ * 3];
    __shared__ __align__(16) float sq[NJ][132];       // padded: 132*4=528 B rows (16B-aligned)
    __shared__ __align__(16) float sk[NJ][132];
    __shared__ __align__(16) float sv[NJ][132];
    __shared__ __align__(16) float sw[NH][NJ][NJ];    // attention weights
    __shared__ __align__(16) float sctxT[DM][20];     // ctx transposed, stride 20 (80 B rows)

    // ---- stage x -------------------------------------------------------
    const float* xp = x + (size_t)pos * (NJ * 3);
    if (t < NJ * 3) sx[t] = xp[t];
    __syncthreads();

    // ---- QKV projection: thread t = output column d --------------------
    {
        const int d = t;
        const float wq0 = Wq[0 * DM + d], wq1 = Wq[1 * DM + d], wq2 = Wq[2 * DM + d];
        const float wk0 = Wk[0 * DM + d], wk1 = Wk[1 * DM + d], wk2 = Wk[2 * DM + d];
        const float wv0 = Wv[0 * DM + d], wv1 = Wv[1 * DM + d], wv2 = Wv[2 * DM + d];
        const float bqd = bq[d], bkd = bk[d], bvd = bv[d];
#pragma unroll
        for (int j = 0; j < NJ; ++j) {
            const float x0 = sx[j * 3 + 0], x1 = sx[j * 3 + 1], x2 = sx[j * 3 + 2];
            sq[j][d] = bqd + x0 * wq0 + x1 * wq1 + x2 * wq2;
            sk[j][d] = bkd + x0 * wk0 + x1 * wk1 + x2 * wk2;
            sv[j][d] = bvd + x0 * wv0 + x1 * wv1 + x2 * wv2;
        }
    }
    __syncthreads();

    // ---- scores + softmax: thread t = (head h, row j) ------------------
    {
        const int h = t >> 4, j = t & 15;
        const int c0 = h * HDIM;
        const float4 q0 = *(const float4*)&sq[j][c0 + 0];
        const float4 q1 = *(const float4*)&sq[j][c0 + 4];
        const float4 q2 = *(const float4*)&sq[j][c0 + 8];
        const float4 q3 = *(const float4*)&sq[j][c0 + 12];

        float sc[NJ];
        float mx = -1e30f;
#pragma unroll
        for (int kk = 0; kk < NJ; ++kk) {
            const float4* kp = (const float4*)&sk[kk][c0];
            float s = dot4(q0, kp[0]) + dot4(q1, kp[1]) + dot4(q2, kp[2]) + dot4(q3, kp[3]);
            // adjacency added BEFORE the 1/sqrt(head_dim) scale (as in reference)
            s = (s + c_adj[j * NJ + kk]) * 0.25f;
            sc[kk] = s;
            mx = fmaxf(mx, s);
        }
        float sum = 0.f;
#pragma unroll
        for (int kk = 0; kk < NJ; ++kk) {
            const float e = __expf(sc[kk] - mx);
            sc[kk] = e;
            sum += e;
        }
        const float inv = 1.f / sum;
#pragma unroll
        for (int kk = 0; kk < NJ; ++kk) sw[h][j][kk] = sc[kk] * inv;
    }
    __syncthreads();

    // ---- ctx = w @ v: thread t = column d; store transposed ------------
    {
        const int d = t, h = d >> 4;
        float vcol[NJ];
#pragma unroll
        for (int kk = 0; kk < NJ; ++kk) vcol[kk] = sv[kk][d];
#pragma unroll
        for (int j = 0; j < NJ; ++j) {
            const float4* wp = (const float4*)&sw[h][j][0];
            const float4 w0 = wp[0], w1 = wp[1], w2 = wp[2], w3 = wp[3];
            float acc;
            acc  = w0.x * vcol[0]  + w0.y * vcol[1]  + w0.z * vcol[2]  + w0.w * vcol[3];
            acc += w1.x * vcol[4]  + w1.y * vcol[5]  + w1.z * vcol[6]  + w1.w * vcol[7];
            acc += w2.x * vcol[8]  + w2.y * vcol[9]  + w2.z * vcol[10] + w2.w * vcol[11];
            acc += w3.x * vcol[12] + w3.y * vcol[13] + w3.z * vcol[14] + w3.w * vcol[15];
            sctxT[d][j] = acc;
        }
    }
    __syncthreads();

    // ---- out = ctx @ Wo + bo: thread t = column d ----------------------
    {
        const int d = t;
        float acc[NJ];
        const float bod = bo[d];
#pragma unroll
        for (int j = 0; j < NJ; ++j) acc[j] = bod;

        for (int e = 0; e < DM; ++e) {
            const float wv = Wo[e * DM + d];
            const float4* cp = (const float4*)&sctxT[e][0];
            const float4 c0 = cp[0], c1 = cp[1], c2 = cp[2], c3 = cp[3];
            acc[0]  += c0.x * wv; acc[1]  += c0.y * wv; acc[2]  += c0.z * wv; acc[3]  += c0.w * wv;
            acc[4]  += c1.x * wv; acc[5]  += c1.y * wv; acc[6]  += c1.z * wv; acc[7]  += c1.w * wv;
            acc[8]  += c2.x * wv; acc[9]  += c2.y * wv; acc[10] += c2.z * wv; acc[11] += c2.w * wv;
            acc[12] += c3.x * wv; acc[13] += c3.y * wv; acc[14] += c3.z * wv; acc[15] += c3.w * wv;
        }

        float* op = out + (size_t)pos * (NJ * DM) + d;
#pragma unroll
        for (int j = 0; j < NJ; ++j) op[j * DM] = acc[j];
    }
}

extern "C" void kernel_launch(void* const* d_in, const int* in_sizes, int n_in,
                              void* d_out, int out_size, void* d_ws, size_t ws_size,
                              hipStream_t stream) {
    const float* x  = (const float*)d_in[0];
    const float* Wq = (const float*)d_in[1];
    const float* bq = (const float*)d_in[2];
    const float* Wk = (const float*)d_in[3];
    const float* bk = (const float*)d_in[4];
    const float* Wv = (const float*)d_in[5];
    const float* bv = (const float*)d_in[6];
    const float* Wo = (const float*)d_in[7];
    const float* bo = (const float*)d_in[8];
    float* out = (float*)d_out;

    const int npos = in_sizes[0] / (NJ * 3);   // B*S = 32768
    skel_attn_kernel<<<npos, 128, 0, stream>>>(x, Wq, bq, Wk, bk, Wv, bv, Wo, bo, out);
}

// Round 2
// 115.602 us; speedup vs baseline: 4.8098x; 4.8098x over previous
//
#include <hip/hip_runtime.h>

#define NJ   16
#define DM   128
#define NH   8
#define HDIM 16
#define P    8          // positions per block
#define NPASS (P/2)

// Kinematic adjacency (compile-time constant of the reference).
__constant__ float c_adj[NJ * NJ] = {
    1,1,0,0, 1,0,0,1, 0,0,1,0, 0,1,0,0,
    1,1,1,0, 0,0,0,0, 0,0,0,0, 0,0,0,0,
    0,1,1,1, 0,0,0,0, 0,0,0,0, 0,0,0,0,
    0,0,1,1, 0,0,0,0, 0,0,0,0, 0,0,0,0,
    1,0,0,0, 1,1,0,0.8f, 0,0,0,0, 0,0,0,0,
    0,0,0,0, 1,1,1,0, 0.8f,0,0,0, 0,0,0,0,
    0,0,0,0, 0,1,1,0, 0,0.8f,0,0, 0,0,0,0,
    1,0,0,0, 0.8f,0,0,1, 1,0,0,0, 0,0,0,0,
    0,0,0,0, 0,0.8f,0,1, 1,1,0,0, 0,0,0,0,
    0,0,0,0, 0,0,0.8f,0, 1,1,0,0, 0,0,0,0,
    1,0,0,0, 0,0,0,0, 0,0,1,1, 0,0.8f,0,0,
    0,0,0,0, 0,0,0,0, 0,0,1,1, 1,0,0.8f,0,
    0,0,0,0, 0,0,0,0, 0,0,0,1, 1,0,0,0.8f,
    1,0,0,0, 0,0,0,0, 0,0,0.8f,0, 0,1,1,0,
    0,0,0,0, 0,0,0,0, 0,0,0,0.8f, 0,1,1,1,
    0,0,0,0, 0,0,0,0, 0,0,0,0, 0.8f,0,1,1
};

// ws layout (floats):
//   [0, 3072)      G[24][128]   : G[h*3+r][n] = sum_dh Wv[r][h*16+dh] * Wo[h*16+dh][n]
//   [3072, 3200)   bprime[128]  : bv @ Wo + bo
//   [3200, 3328)   pack[8][16]  : per head: M(9, row-major), a(3), c(3), d(1)
#define WS_BP   3072
#define WS_PACK 3200

__global__ __launch_bounds__(128) void skel_setup_kernel(
    const float* __restrict__ Wq, const float* __restrict__ bq,
    const float* __restrict__ Wk, const float* __restrict__ bk,
    const float* __restrict__ Wv, const float* __restrict__ bv,
    const float* __restrict__ Wo, const float* __restrict__ bo,
    float* __restrict__ ws)
{
    const int n = threadIdx.x;   // 0..127
    // G columns
    for (int hr = 0; hr < 24; ++hr) {
        const int h = hr / 3, r = hr % 3;
        float acc = 0.f;
#pragma unroll
        for (int dh = 0; dh < HDIM; ++dh)
            acc += Wv[r * DM + h * HDIM + dh] * Wo[(h * HDIM + dh) * DM + n];
        ws[hr * DM + n] = acc;
    }
    // b' column
    {
        float b = bo[n];
        for (int d = 0; d < DM; ++d) b += bv[d] * Wo[d * DM + n];
        ws[WS_BP + n] = b;
    }
    // per-head packs
    if (n < NH) {
        const int h = n;
        float* o = &ws[WS_PACK + h * 16];
#pragma unroll
        for (int r = 0; r < 3; ++r)
#pragma unroll
            for (int c = 0; c < 3; ++c) {
                float acc = 0.f;
#pragma unroll
                for (int dh = 0; dh < HDIM; ++dh)
                    acc += Wq[r * DM + h * HDIM + dh] * Wk[c * DM + h * HDIM + dh];
                o[r * 3 + c] = acc;
            }
#pragma unroll
        for (int r = 0; r < 3; ++r) {
            float aa = 0.f, cc = 0.f;
#pragma unroll
            for (int dh = 0; dh < HDIM; ++dh) {
                aa += Wq[r * DM + h * HDIM + dh] * bk[h * HDIM + dh];
                cc += Wk[r * DM + h * HDIM + dh] * bq[h * HDIM + dh];
            }
            o[9 + r]  = aa;
            o[12 + r] = cc;
        }
        float dd = 0.f;
#pragma unroll
        for (int dh = 0; dh < HDIM; ++dh) dd += bq[h * HDIM + dh] * bk[h * HDIM + dh];
        o[15] = dd;
    }
}

__global__ __launch_bounds__(256) void skel_main_kernel(
    const float* __restrict__ x,
    const float* __restrict__ ws,
    float* __restrict__ out,
    int npos)
{
    const int t = threadIdx.x;
    const long pos0 = (long)blockIdx.x * P;

    __shared__ float sx[P][48];                       // x per position
    __shared__ float sc[128];                         // per-head packs
    __shared__ __align__(16) float st[2][NH][17][4];  // {M x_k (3), c·x_k + d} ; k-dim padded 16->17
    __shared__ __align__(16) float sXB[P * NJ][24];   // xbar rows (96 B each, 16B-aligned)

    // ---- stage x and constants ----------------------------------------
    for (int i = t; i < P * 48; i += 256) {
        const long gi = pos0 * 48 + i;
        sx[i / 48][i % 48] = (gi < (long)npos * 48) ? x[gi] : 0.f;
    }
    if (t < 128) sc[t] = ws[WS_PACK + t];
    __syncthreads();

    const int p2  = t >> 7;          // 0..1 (wave-uniform)
    const int rem = t & 127;
    const int h   = rem >> 4;
    const int kj  = rem & 15;        // doubles as k (t-phase) and j (score phase)
    const float* Mh = &sc[h * 16];

    for (int pass = 0; pass < NPASS; ++pass) {
        const int p = pass * 2 + p2;
        const float x0 = sx[p][kj * 3 + 0];
        const float x1 = sx[p][kj * 3 + 1];
        const float x2 = sx[p][kj * 3 + 2];

        // t-phase: t_k = M_h x_k ; e_k = c_h·x_k + d_h
        st[p2][h][kj][0] = Mh[0] * x0 + Mh[1] * x1 + Mh[2] * x2;
        st[p2][h][kj][1] = Mh[3] * x0 + Mh[4] * x1 + Mh[5] * x2;
        st[p2][h][kj][2] = Mh[6] * x0 + Mh[7] * x1 + Mh[8] * x2;
        st[p2][h][kj][3] = Mh[12] * x0 + Mh[13] * x1 + Mh[14] * x2 + Mh[15];
        __syncthreads();

        // score phase: j = kj; this thread's (x0,x1,x2) IS x_j
        const int j = kj;
        const float u = Mh[9] * x0 + Mh[10] * x1 + Mh[11] * x2;   // a_h·x_j

        float s[NJ];
        float mx = -1e30f;
#pragma unroll
        for (int k = 0; k < NJ; ++k) {
            const float4 tk = *(const float4*)&st[p2][h][k][0];
            float sv = x0 * tk.x + x1 * tk.y + x2 * tk.z + tk.w + u;
            sv = (sv + c_adj[j * NJ + k]) * 0.25f;
            s[k] = sv;
            mx = fmaxf(mx, sv);
        }
        float sum = 0.f;
#pragma unroll
        for (int k = 0; k < NJ; ++k) {
            const float e = __expf(s[k] - mx);
            s[k] = e;
            sum += e;
        }
        const float inv = 1.f / sum;

        // xbar_{h,j} = sum_k w_jk x_k
        float xb0 = 0.f, xb1 = 0.f, xb2 = 0.f;
#pragma unroll
        for (int k = 0; k < NJ; ++k) {
            const float wk = s[k] * inv;
            xb0 += wk * sx[p][k * 3 + 0];
            xb1 += wk * sx[p][k * 3 + 1];
            xb2 += wk * sx[p][k * 3 + 2];
        }
        float* xbp = &sXB[p * NJ + j][h * 3];
        xbp[0] = xb0; xbp[1] = xb1; xbp[2] = xb2;
        __syncthreads();   // protects st for next pass; publishes sXB
    }

    // ---- out phase: out[r][n] = b'[n] + sum_hr XB[r][hr] * G[hr][n] ----
    const int half = t >> 7;
    const int n    = rem;
    float g[24];
#pragma unroll
    for (int hr = 0; hr < 24; ++hr) g[hr] = ws[hr * DM + n];
    const float bp = ws[WS_BP + n];

    const int rbase = half * 64;
    for (int r0 = 0; r0 < 64; r0 += 4) {
        float acc[4];
#pragma unroll
        for (int i = 0; i < 4; ++i) acc[i] = bp;
#pragma unroll
        for (int i = 0; i < 4; ++i) {
            const float4* xq = (const float4*)&sXB[rbase + r0 + i][0];
#pragma unroll
            for (int q = 0; q < 6; ++q) {
                const float4 xb = xq[q];
                acc[i] += xb.x * g[4 * q + 0] + xb.y * g[4 * q + 1]
                        + xb.z * g[4 * q + 2] + xb.w * g[4 * q + 3];
            }
        }
#pragma unroll
        for (int i = 0; i < 4; ++i) {
            const int r = rbase + r0 + i;            // = p*16 + j
            const long pidx = pos0 + (r >> 4);
            if (pidx < npos)
                out[pos0 * (NJ * DM) + (long)r * DM + n] = acc[i];
        }
    }
}

extern "C" void kernel_launch(void* const* d_in, const int* in_sizes, int n_in,
                              void* d_out, int out_size, void* d_ws, size_t ws_size,
                              hipStream_t stream) {
    const float* x  = (const float*)d_in[0];
    const float* Wq = (const float*)d_in[1];
    const float* bq = (const float*)d_in[2];
    const float* Wk = (const float*)d_in[3];
    const float* bk = (const float*)d_in[4];
    const float* Wv = (const float*)d_in[5];
    const float* bv = (const float*)d_in[6];
    const float* Wo = (const float*)d_in[7];
    const float* bo = (const float*)d_in[8];
    float* out = (float*)d_out;
    float* ws  = (float*)d_ws;

    const int npos = in_sizes[0] / (NJ * 3);   // B*S
    skel_setup_kernel<<<1, 128, 0, stream>>>(Wq, bq, Wk, bk, Wv, bv, Wo, bo, ws);
    const int grid = (npos + P - 1) / P;
    skel_main_kernel<<<grid, 256, 0, stream>>>(x, ws, out, npos);
}